// Round 2
// baseline (424.603 us; speedup 1.0000x reference)
//
#include <hip/hip_runtime.h>

// HiearchicalFFTShiftModel: closed-form spectrum with EXACT emulation of the
// reference's complex64 phase quantization, + 3-pass 2^24 complex IFFT (c2r packing).
//
// Reference stage i (size n=2^{i+1}, n_coeffs=2^i+1) multiplies rfft bin K by
//   exp(i*theta_i(K)),  theta_i(K) = fl32( fl32(K * c_i) * s_i )
//   c_i = fl32(2*pi/(2^i+1))        (complex64 cast of the double scalar)
//   s_i = fl32(1 - e_i*2^-i) * 2^i  (float32 shift_samples; only 1-x rounds)
// Folding final bin k down the stages (integer-exact bookkeeping):
//   S[k] = T_t * prod_{i=t+1}^{23} exp(i*sgn(sd_i)*theta_i(|sd_i|)) * exp(i*theta_24(k))
//   t = ctz(k), sd_i = ((k+2^i) mod 2^{i+1}) - 2^i, T_t = cos(theta_t(2^t))
//   S[m-k] uses the conjugate of the shared i<=23 chain (sd flips sign) and theta_24(m-k).
// c2r pack: W[j] = A + i*e^{2*pi*i*j/N}*B, A=S[j]+conj(S[m-j]), B=S[j]-conj(S[m-j]);
//   W[m-k] = conj(A_k - i*C_k), C = e^{i*2*pi*k/N} * B. z=IDFT_m(W)/N interleaved = out.

constexpr float PI_F    = 3.14159265358979323846f;
constexpr float TWOPI_F = 6.28318530717958647692f;
constexpr unsigned M24 = 1u << 24;

__device__ __forceinline__ void phase_sincos(float th, float* sn, float* cs) {
    // Accurate sin/cos of the float32 value th (|th| up to ~1.1e8):
    // reduce mod 2*pi in double, evaluate in float.
    double d = (double)th * 0.15915494309189533577;  // 1/(2*pi)
    d -= rint(d);                                    // frac in [-0.5, 0.5]
    float ang = (float)(d * 6.2831853071795864769);  // [-pi, pi]
    __sincosf(ang, sn, cs);
}

// ---------------- Kernel A: build W[k] (packed c2r spectrum), scaled by 1/N ----------------
__global__ __launch_bounds__(256) void build_w(const float* __restrict__ el,
                                               float2* __restrict__ W) {
    __shared__ float c_s[25], s_s[25], T_s[24];
    int tid = threadIdx.x;
    if (tid < 25) {
        float e = el[tid];
        float shift1 = e * (1.0f / (float)(1u << tid));   // exact (pow2 scale)
        float sh2 = 1.0f - shift1;                        // THE float32 rounding
        float s = sh2 * (float)(1u << tid);               // exact
        float c = (float)(6.2831853071795864769 / (double)((1u << tid) + 1u));
        c_s[tid] = c;
        s_s[tid] = s;
        if (tid < 24) {
            float p  = (float)(1u << tid) * c;            // exact pow2 scale
            float th = p * s;                             // fl32
            float sn, cs; phase_sincos(th, &sn, &cs);
            T_s[tid] = cs;                                // terminal nyquist value
        }
    }
    __syncthreads();

    unsigned k = blockIdx.x * 256u + (unsigned)tid;
    if (k > 8388608u) return;                             // k in [0, 2^23]

    const float sc = 1.0f / 33554432.0f;                  // 1/N

    if (k == 0u) {
        // S[0]=1 ; S[m]=cos(theta_24(2^24))
        float p  = 16777216.0f * c_s[24];                 // exact pow2 scale
        float th = p * s_s[24];
        float sn, cs; phase_sincos(th, &sn, &cs);
        float Smr = cs;
        W[0] = make_float2((1.0f + Smr) * sc, (1.0f - Smr) * sc);
        return;
    }

    unsigned t = (unsigned)__builtin_ctz(k);              // t <= 23
    float Pr = T_s[t], Pi = 0.0f;

#pragma unroll
    for (int i = 1; i <= 23; ++i) {
        unsigned hi = 1u << i;
        int sd = (int)((k + hi) & (2u * hi - 1u)) - (int)hi;
        int K  = (i <= (int)t) ? 0 : (sd < 0 ? -sd : sd); // identity factor if i<=t
        float sgn = (sd < 0) ? -1.0f : 1.0f;
        float p  = (float)K * c_s[i];                     // fl32(K*c_i)
        float th = p * s_s[i];                            // fl32(.. * s_i)
        float sn, cs; phase_sincos(th, &sn, &cs);
        float ssn = sgn * sn;
        float nr = Pr * cs - Pi * ssn;
        float ni = Pr * ssn + Pi * cs;
        Pr = nr; Pi = ni;
    }

    // level 24 factors (indices are the raw bins, never folded, sign +)
    unsigned mk = M24 - k;
    float thk = ((float)k  * c_s[24]) * s_s[24];
    float thm = ((float)mk * c_s[24]) * s_s[24];
    float snk, csk, snm, csm;
    phase_sincos(thk, &snk, &csk);
    phase_sincos(thm, &snm, &csm);

    float Skr = Pr * csk - Pi * snk;
    float Ski = Pr * snk + Pi * csk;
    float Smr = Pr * csm + Pi * snm;                      // conj(P) * e^{i*thm}
    float Smi = Pr * snm - Pi * csm;

    // c2r packing
    float Ar = Skr + Smr, Ai = Ski - Smi;
    float Br = Skr - Smr, Bi = Ski + Smi;
    float ang = (float)k * (TWOPI_F / 33554432.0f);       // 2*pi*k/N in [0, pi/2]
    float ts, tc; __sincosf(ang, &ts, &tc);
    float Cr = tc * Br - ts * Bi;
    float Ci = ts * Br + tc * Bi;

    W[k] = make_float2((Ar - Ci) * sc, (Ai + Cr) * sc);
    if (k != 8388608u)
        W[mk] = make_float2((Ar + Ci) * sc, (Cr - Ai) * sc);
}

// ---------------- shared radix-2 in-place DIF inverse FFT over 16 rows x 256 ----------------
// Output lands bit-reversed within each row: position p holds X[brev8(p)].
__device__ __forceinline__ void fft256x16_inv(float2 (*lds)[257], int tid) {
#pragma unroll
    for (int half = 128; half >= 1; half >>= 1) {
        float astep = PI_F / (float)half;    // e^{+i*pi*j/half} twiddle (inverse)
        __syncthreads();
#pragma unroll
        for (int u = 0; u < 8; ++u) {
            int b   = tid + 256 * u;
            int row = b >> 7;
            int idx = b & 127;
            int j   = idx & (half - 1);
            int p0  = 2 * idx - j;
            float2 x0 = lds[row][p0];
            float2 x1 = lds[row][p0 + half];
            float2 sum = make_float2(x0.x + x1.x, x0.y + x1.y);
            float2 dif = make_float2(x0.x - x1.x, x0.y - x1.y);
            float s, c;
            __sincosf(astep * (float)j, &s, &c);
            lds[row][p0]        = sum;
            lds[row][p0 + half] = make_float2(dif.x * c - dif.y * s,
                                              dif.x * s + dif.y * c);
        }
    }
    __syncthreads();
}

// ---------------- Stage A: IDFT over k3 (stride 65536) ----------------
__global__ __launch_bounds__(256) void fft_stage_a(const float2* __restrict__ in,
                                                   float2* __restrict__ out) {
    __shared__ float2 lds[16][257];
    int tid   = threadIdx.x;
    int cbase = blockIdx.x * 16;           // c = k1 + 256*k2, 16 consecutive per WG
#pragma unroll
    for (int u = 0; u < 16; ++u) {
        int e = tid + 256 * u;
        int row = e & 15, k3 = e >> 4;
        lds[row][k3] = in[cbase + row + (k3 << 16)];
    }
    fft256x16_inv(lds, tid);
#pragma unroll
    for (int u = 0; u < 16; ++u) {
        int e = tid + 256 * u;
        int row = e & 15, p = e >> 4;
        int t3 = (int)(__brev((unsigned)p) >> 24);
        out[cbase + row + (t3 << 16)] = lds[row][p];
    }
}

// ---------------- Stage B: twiddle e^{2*pi*i*t3*k2/65536}, IDFT over k2 (stride 256) ----------------
__global__ __launch_bounds__(256) void fft_stage_b(const float2* __restrict__ in,
                                                   float2* __restrict__ out) {
    __shared__ float2 lds[16][257];
    int tid = threadIdx.x;
    int wg  = blockIdx.x;
    int k1b = (wg & 15) * 16;
    int t3  = wg >> 4;
    const float tsc = TWOPI_F / 65536.0f;
#pragma unroll
    for (int u = 0; u < 16; ++u) {
        int e = tid + 256 * u;
        int row = e & 15, k2 = e >> 4;
        float2 v = in[k1b + row + (k2 << 8) + (t3 << 16)];
        float s, c;
        __sincosf(tsc * (float)(t3 * k2), &s, &c);
        lds[row][k2] = make_float2(v.x * c - v.y * s, v.x * s + v.y * c);
    }
    fft256x16_inv(lds, tid);
#pragma unroll
    for (int u = 0; u < 16; ++u) {
        int e = tid + 256 * u;
        int row = e & 15, p = e >> 4;
        int t2 = (int)(__brev((unsigned)p) >> 24);
        out[k1b + row + (t2 << 8) + (t3 << 16)] = lds[row][p];
    }
}

// ---------------- Stage C: twiddle e^{2*pi*i*(t3+256*t2)*k1/2^24}, IDFT over k1 (stride 1) ----------------
__global__ __launch_bounds__(256) void fft_stage_c(const float2* __restrict__ in,
                                                   float2* __restrict__ out) {
    __shared__ float2 lds[16][257];
    int tid = threadIdx.x;
    int wg  = blockIdx.x;
    int t3b = (wg & 15) * 16;
    int t2  = wg >> 4;
    const float tsc = TWOPI_F / 16777216.0f;
#pragma unroll
    for (int u = 0; u < 16; ++u) {
        int e = tid + 256 * u;
        int k1 = e & 255, r = e >> 8;
        float2 v = in[k1 + (t2 << 8) + ((t3b + r) << 16)];
        float s, c;
        __sincosf(tsc * (float)((t3b + r + (t2 << 8)) * k1), &s, &c);
        lds[r][k1] = make_float2(v.x * c - v.y * s, v.x * s + v.y * c);
    }
    fft256x16_inv(lds, tid);
#pragma unroll
    for (int u = 0; u < 16; ++u) {
        int e = tid + 256 * u;
        int r = e & 15, p = e >> 4;
        int t1 = (int)(__brev((unsigned)p) >> 24);
        out[(t3b + r) + (t2 << 8) + (t1 << 16)] = lds[r][p];
    }
}

extern "C" void kernel_launch(void* const* d_in, const int* in_sizes, int n_in,
                              void* d_out, int out_size, void* d_ws, size_t ws_size,
                              hipStream_t stream) {
    const float* el = (const float*)d_in[0];   // 25 floats
    float2* W  = (float2*)d_ws;                // 2^24 float2 = 128 MiB scratch
    float2* Gd = (float2*)d_out;               // out buffer doubles as complex ping-pong

    // build W (ws) -> stageA: ws->out -> stageB: out->ws -> stageC: ws->out (final real signal)
    hipLaunchKernelGGL(build_w,     dim3(32769), dim3(256), 0, stream, el, W);
    hipLaunchKernelGGL(fft_stage_a, dim3(4096),  dim3(256), 0, stream, W, Gd);
    hipLaunchKernelGGL(fft_stage_b, dim3(4096),  dim3(256), 0, stream, Gd, W);
    hipLaunchKernelGGL(fft_stage_c, dim3(4096),  dim3(256), 0, stream, W, Gd);
}